// Round 15
// baseline (292.488 us; speedup 1.0000x reference)
//
#include <hip/hip_runtime.h>
#include <hip/hip_bf16.h>

#define NIMG 8
#define NC   80
#define NL   256
#define HWQ  15200
#define TOPK 1000
#define CAP  4096
#define SSORT 2048
#define NPOST 100
#define PERIMG (HWQ * NC)          // 1,216,000
#define TOTAL (NIMG * PERIMG)      // 9,728,000
#define SROW 32                    // rows per score block
#define SBLK32 (NIMG * HWQ / SROW) // 3800
#define BPI (HWQ / SROW)           // 475 score blocks per image
#define PI4  (PERIMG / 4)          // 304,000 float4 per image
#define WPI  (PI4 / 64)            // 4750 waves per image
#define NWAVE (NIMG * WPI)         // 38,000
#define CBLK (TOTAL / 4 / 256)     // 9,500 blocks for count pass

__device__ __forceinline__ unsigned flipKey(float f) {
    unsigned u = __float_as_uint(f);
    return u ^ (((unsigned)((int)u >> 31)) | 0x80000000u);
}
__device__ __forceinline__ float unflipKey(unsigned k) {
    unsigned u = k ^ ((k & 0x80000000u) ? 0x80000000u : 0xFFFFFFFFu);
    return __uint_as_float(u);
}
__device__ __forceinline__ float sigmoidf(float x) {
    return 1.0f / (1.0f + expf(-x));
}

// ---- init: zero coarse histograms + done counters + extract token lists ----
__global__ void __launch_bounds__(256)
kinit(const float* __restrict__ pm, unsigned* nnz, unsigned* tok, float* wt,
      unsigned* __restrict__ gh, unsigned* __restrict__ done) {
    int g = blockIdx.x * 256 + threadIdx.x;
    if (g < NIMG * 4096) gh[g] = 0;            // 32768 threads == exact
    if (g < NIMG) done[g] = 0;
    if (g < NC) {
        int c = g;
        int cnt = 0;
        for (int l = 0; l < NL; ++l) {
            float v = pm[c * NL + l];
            if (v != 0.0f) { tok[cnt * NC + c] = l; wt[cnt * NC + c] = v; cnt++; }
        }
        nnz[c] = cnt;
    }
}

// ---- fused scores + centerness + coarse 12-bit histogram (v3) + inline
//      per-image find (last-block-done; atomic reads of gh for XCD safety) ----
__global__ void __launch_bounds__(512)
kscoreh(const float* __restrict__ dp, const float* __restrict__ cent,
        const unsigned* __restrict__ nnz, const unsigned* __restrict__ tok,
        const float* __restrict__ wt, float* __restrict__ scores,
        unsigned* __restrict__ gh, unsigned* __restrict__ done,
        unsigned* __restrict__ meta) {
    __shared__ unsigned h[4096];        // 16 KB
    __shared__ float sctr[SROW];
    __shared__ unsigned psum[256];
    __shared__ int lastFlag;
    int t = threadIdx.x;
    for (int i = t; i < 4096; i += 512) h[i] = 0;
    long long base = (long long)blockIdx.x * SROW;        // first global row
    if (t < SROW) sctr[t] = sigmoidf(cent[base + t]);     // once per row
    long long obase = base * NC;
    const float* dpb = dp + base * NL;

    int  rr[5], cc[5], mm[5];
    int  tk[5][3];
    float wv[5][3], xv[5][3];
#pragma unroll
    for (int j = 0; j < 5; ++j) {
        int o = t + j * 512;            // 0..2559 (32 rows x 80 classes)
        rr[j] = o / NC; cc[j] = o - rr[j] * NC;
        mm[j] = (int)nnz[cc[j]];
        int c = cc[j];
        tk[j][0] = (int)tok[c] & 255;           // clamp: safe vs stale ws
        tk[j][1] = (int)tok[NC + c] & 255;
        tk[j][2] = (int)tok[2 * NC + c] & 255;
        wv[j][0] = wt[c]; wv[j][1] = wt[NC + c]; wv[j][2] = wt[2 * NC + c];
    }
#pragma unroll
    for (int j = 0; j < 5; ++j) {       // all gathers issued before any exp
        const float* row = dpb + rr[j] * NL;
        if (tk[j][1] == tk[j][0] + 1 && tk[j][2] == tk[j][0] + 2) {
            float3 v3 = *(const float3*)(row + tk[j][0]);   // 1 VMEM, 12B
            xv[j][0] = v3.x; xv[j][1] = v3.y; xv[j][2] = v3.z;
        } else {
            xv[j][0] = row[tk[j][0]];
            xv[j][1] = row[tk[j][1]];
            xv[j][2] = row[tk[j][2]];
        }
    }
    __syncthreads();                    // sctr ready; hist zeroed
#pragma unroll
    for (int j = 0; j < 5; ++j) {
        float acc = 0.0f;
        if (mm[j] == 3) {               // identical arithmetic to prior rounds
            float s0 = sigmoidf(xv[j][0]);
            float s1 = sigmoidf(xv[j][1]);
            float s2 = sigmoidf(xv[j][2]);
            acc += s0 * wv[j][0]; acc += s1 * wv[j][1]; acc += s2 * wv[j][2];
        } else {
            const float* row = dpb + rr[j] * NL;
            for (int q = 0; q < mm[j]; ++q)
                acc += sigmoidf(row[tok[q * NC + cc[j]]]) * wt[q * NC + cc[j]];
        }
        float sc = (acc > 0.05f) ? acc * sctr[rr[j]] : -1.0f;
        scores[obase + t + j * 512] = sc;
        atomicAdd(&h[flipKey(sc) >> 20], 1u);
    }
    __syncthreads();
    int n = (int)(base / HWQ);          // 475 blocks per image exactly
    for (int i = t; i < 4096; i += 512)
        if (h[i]) atomicAdd(&gh[n * 4096 + i], h[i]);
    __syncthreads();                    // all gh atomics issued+drained

    // last-finishing block of this image computes meta (exact kfind1 logic)
    if (t == 0) {
        __threadfence();
        lastFlag = (atomicAdd(&done[n], 1u) == BPI - 1) ? 1 : 0;
    }
    __syncthreads();
    if (!lastFlag) return;
    // re-read final gh via device-scope atomic reads (cross-XCD safe)
    for (int i = t; i < 4096; i += 512)
        h[i] = atomicAdd(&gh[n * 4096 + i], 0u);
    __syncthreads();
    if (t < 256) {
        unsigned s = 0;
        for (int i = 0; i < 16; ++i) s += h[t * 16 + i];
        psum[t] = s;
    }
    __syncthreads();
    if (t == 0) {
        unsigned cum = 0, above = 0; int B = 0; bool fdone = false;
        for (int seg = 255; seg >= 0 && !fdone; --seg) {
            if (cum + psum[seg] >= TOPK) {
                for (int b = seg * 16 + 15; b >= seg * 16; --b) {
                    if (cum + h[b] >= TOPK) { B = b; above = cum; fdone = true; break; }
                    cum += h[b];
                }
            } else cum += psum[seg];
        }
        meta[n] = (unsigned)B;
        meta[8 + n] = above;
    }
}

// ---- count pass with per-wave 256-bit selection masks (atomic-free) ----
__global__ void __launch_bounds__(256)
kcountM(const float4* __restrict__ scores4, const unsigned* __restrict__ meta,
        unsigned* __restrict__ wavecnt, unsigned long long* __restrict__ wavemask) {
    int i4 = blockIdx.x * 256 + threadIdx.x;
    int n = i4 / PI4;                 // wave-uniform (64 | PI4)
    unsigned B = meta[n];
    float4 v = scores4[i4];
    bool s0 = (flipKey(v.x) >> 20) >= B;
    bool s1 = (flipKey(v.y) >> 20) >= B;
    bool s2 = (flipKey(v.z) >> 20) >= B;
    bool s3 = (flipKey(v.w) >> 20) >= B;
    unsigned long long m0 = __ballot(s0);
    unsigned long long m1 = __ballot(s1);
    unsigned long long m2 = __ballot(s2);
    unsigned long long m3 = __ballot(s3);
    if ((threadIdx.x & 63) == 0) {
        int w = i4 >> 6;
        wavemask[(size_t)w * 4 + 0] = m0;
        wavemask[(size_t)w * 4 + 1] = m1;
        wavemask[(size_t)w * 4 + 2] = m2;
        wavemask[(size_t)w * 4 + 3] = m3;
        wavecnt[w] = (unsigned)(__popcll(m0) + __popcll(m1)
                              + __popcll(m2) + __popcll(m3));
    }
}

// ---- merged gather: wave-shfl prefix (2 barriers), gather into LDS,
//      sort, emit exact top-1000; global-cand fallback if total > SSORT ----
__global__ void __launch_bounds__(1024)
kgather(const unsigned* __restrict__ wavecnt,
        const unsigned long long* __restrict__ wavemask,
        const float* __restrict__ scores, const unsigned* __restrict__ meta,
        unsigned long long* __restrict__ cand,
        unsigned long long* __restrict__ sorted) {
    __shared__ unsigned ps16[17];
    __shared__ unsigned long long sbuf[SSORT];   // 16 KB
    __shared__ unsigned h[4096];                 // 16 KB (fallback only)
    __shared__ unsigned psum[256];
    __shared__ unsigned selcnt, Fbin;
    int n = blockIdx.x, t = threadIdx.x;
    int lane = t & 63, wid = t >> 6;
    const unsigned* wc = wavecnt + n * WPI;
    const unsigned long long* wm = wavemask + (size_t)n * WPI * 4;
    const float* sb = scores + (size_t)n * PERIMG;
    sbuf[t] = 0ULL; sbuf[t + 1024] = 0ULL;

    // per-thread sums over 5 wave-slots
    int s0 = t * 5;                    // 5*1024 = 5120 >= 4750
    unsigned loc[5], vv[5]; unsigned sum = 0;
#pragma unroll
    for (int j = 0; j < 5; ++j) {
        int i = s0 + j;
        unsigned x = (i < WPI) ? wc[i] : 0u;
        vv[j] = x; loc[j] = sum; sum += x;
    }
    // wave-level inclusive scan of sum (no barriers)
    unsigned wincl = sum;
#pragma unroll
    for (int off = 1; off < 64; off <<= 1) {
        unsigned o = (unsigned)__shfl_up((int)wincl, off);
        if (lane >= off) wincl += o;
    }
    if (lane == 63) ps16[wid] = wincl;
    __syncthreads();
    if (t == 0) {
        unsigned c = 0;
        for (int w = 0; w < 16; ++w) { unsigned x = ps16[w]; ps16[w] = c; c += x; }
        ps16[16] = c;
    }
    __syncthreads();
    unsigned excl = ps16[wid] + (wincl - sum);
    unsigned total = ps16[16];
    int nsel;

    if (total <= SSORT) {
        // common path: gather straight into the LDS sort buffer
#pragma unroll
        for (int j = 0; j < 5; ++j) {
            int wl = s0 + j;
            if (wl < WPI && vv[j]) {
                unsigned off = excl + loc[j];
                const unsigned long long* mk = wm + (size_t)wl * 4;
#pragma unroll
                for (int e = 0; e < 4; ++e) {
                    unsigned long long m = mk[e];
                    while (m) {
                        int b = __ffsll(m) - 1; m &= m - 1;
                        int li = wl * 256 + b * 4 + e;
                        unsigned key = flipKey(sb[li]);
                        sbuf[off++] = ((unsigned long long)key << 32)
                                      | (unsigned)(~li);
                    }
                }
            }
        }
        nsel = (int)total;
        __syncthreads();
    } else {
        // fallback: gather to global cand, then fine-threshold select
        unsigned long long* cb = cand + (size_t)n * CAP;
#pragma unroll
        for (int j = 0; j < 5; ++j) {
            int wl = s0 + j;
            if (wl < WPI && vv[j]) {
                unsigned off = excl + loc[j];
                const unsigned long long* mk = wm + (size_t)wl * 4;
#pragma unroll
                for (int e = 0; e < 4; ++e) {
                    unsigned long long m = mk[e];
                    while (m) {
                        int b = __ffsll(m) - 1; m &= m - 1;
                        int li = wl * 256 + b * 4 + e;
                        unsigned key = flipKey(sb[li]);
                        if (off < CAP)
                            cb[off] = ((unsigned long long)key << 32)
                                      | (unsigned)(~li);
                        off++;
                    }
                }
            }
        }
        for (int i = t; i < 4096; i += 1024) h[i] = 0;
        if (t == 0) selcnt = 0;
        __syncthreads();
        int M = min((int)total, CAP);
        unsigned B = meta[n], above = meta[8 + n];
        for (int i = t; i < M; i += 1024) {
            unsigned key = (unsigned)(cb[i] >> 32);
            if ((key >> 20) == B) atomicAdd(&h[(key >> 8) & 0xFFFu], 1u);
        }
        __syncthreads();
        if (t < 256) {
            unsigned s = 0;
            for (int i = 0; i < 16; ++i) s += h[t * 16 + i];
            psum[t] = s;
        }
        __syncthreads();
        if (t == 0) {
            unsigned cum = above; int F = 0; bool done = false;
            for (int seg = 255; seg >= 0 && !done; --seg) {
                if (cum + psum[seg] >= TOPK) {
                    for (int b = seg * 16 + 15; b >= seg * 16; --b) {
                        if (cum + h[b] >= TOPK) { F = b; done = true; break; }
                        cum += h[b];
                    }
                } else cum += psum[seg];
            }
            Fbin = (unsigned)F;
        }
        __syncthreads();
        unsigned T24 = (meta[n] << 12) | Fbin;
        for (int i = t; i < M; i += 1024) {
            unsigned long long e = cb[i];
            unsigned key = (unsigned)(e >> 32);
            if ((key >> 8) >= T24) {
                unsigned p = atomicAdd(&selcnt, 1u);
                if (p < SSORT) sbuf[p] = e;
            }
        }
        __syncthreads();
        nsel = (int)selcnt;
    }

    // bitonic sort descending on unique (key<<32)|~idx
    int SN = (nsel <= 1024) ? 1024 : SSORT;
    for (int k = 2; k <= SN; k <<= 1) {
        for (int j = k >> 1; j > 0; j >>= 1) {
            for (int i = t; i < SN; i += 1024) {
                int l = i ^ j;
                if (l > i) {
                    unsigned long long a = sbuf[i], b = sbuf[l];
                    bool sw = ((i & k) == 0) ? (a < b) : (a > b);
                    if (sw) { sbuf[i] = b; sbuf[l] = a; }
                }
            }
            __syncthreads();
        }
    }
    if (t < TOPK) sorted[(n << 10) + t] = sbuf[t];
}

// ---- decode all 8x1000 candidates chip-wide ----
__global__ void __launch_bounds__(256)
kdecode(const unsigned long long* __restrict__ sorted,
        const float* __restrict__ anchors, const float* __restrict__ breg,
        float4* __restrict__ box4, float4* __restrict__ obx4,
        float* __restrict__ areag, unsigned* __restrict__ lblkeep) {
    int gid = blockIdx.x * 256 + threadIdx.x;
    if (gid >= NIMG * TOPK) return;
    int n = gid / TOPK, r = gid - n * TOPK;
    int o = (n << 10) + r;
    unsigned long long e = sorted[o];
    unsigned key = (unsigned)(e >> 32);
    bool real = key > 0x80000000u;       // masked value > 0
    unsigned li = ~(unsigned)(e & 0xFFFFFFFFu);
    unsigned k = li / NC, c = li - k * NC;
    int label = (int)c + 1;
    float x1 = 0, y1 = 0, x2 = 0, y2 = 0;
    bool val = false;
    if (real) {
        float a0 = anchors[k * 4 + 0], a1 = anchors[k * 4 + 1];
        float a2 = anchors[k * 4 + 2], a3 = anchors[k * 4 + 3];
        float r0 = breg[(n * 4 + 0) * HWQ + k];
        float r1 = breg[(n * 4 + 1) * HWQ + k];
        float r2 = breg[(n * 4 + 2) * HWQ + k];
        float r3 = breg[(n * 4 + 3) * HWQ + k];
        float aw = a2 - a0, ah = a3 - a1;
        float acx = a0 + 0.5f * aw, acy = a1 + 0.5f * ah;
        float dx = r0 / 10.0f, dy = r1 / 10.0f;
        float dw = fminf(r2 / 5.0f, 4.135166556742356f);
        float dh = fminf(r3 / 5.0f, 4.135166556742356f);
        float pcx = dx * aw + acx, pcy = dy * ah + acy;
        float pw = expf(dw) * aw, ph = expf(dh) * ah;
        x1 = fminf(fmaxf(pcx - 0.5f * pw, 0.0f), 1216.0f);
        y1 = fminf(fmaxf(pcy - 0.5f * ph, 0.0f), 800.0f);
        x2 = fminf(fmaxf(pcx + 0.5f * pw, 0.0f), 1216.0f);
        y2 = fminf(fmaxf(pcy + 0.5f * ph, 0.0f), 800.0f);
        val = (x2 - x1 > 0.0f) && (y2 - y1 > 0.0f);
    }
    box4[o] = make_float4(x1, y1, x2, y2);
    float off = (float)label * 10000.0f;   // replicate offset-then-round
    float o0 = x1 + off, o1 = y1 + off, o2 = x2 + off, o3 = y2 + off;
    obx4[o] = make_float4(o0, o1, o2, o3);
    areag[o] = (o2 - o0) * (o3 - o1);
    lblkeep[o] = (unsigned)(real ? label : 0) | ((val ? 1u : 0u) << 16);
}

// ---- per-image: class-decomposed bitmask NMS + output (bitset ranks,
//      wave-shfl keep-prefix: 2 barriers instead of 20) ----
__global__ void __launch_bounds__(1024)
knms2(const unsigned long long* __restrict__ sorted,
      const float4* __restrict__ obx4, const float* __restrict__ areag,
      const unsigned* __restrict__ lblkeep, const float4* __restrict__ box4,
      float* __restrict__ outBoxes, float* __restrict__ outScores,
      float* __restrict__ outLabels) {
    __shared__ float ob0[TOPK], ob1[TOPK], ob2[TOPK], ob3[TOPK], area[TOPK];
    __shared__ unsigned long long sup[TOPK];
    __shared__ unsigned long long cbits[NC * 16];   // 10,240 B class bitsets
    __shared__ unsigned short lbl[TOPK];
    __shared__ unsigned char  keepf[TOPK];
    __shared__ unsigned short wrank[TOPK];
    __shared__ unsigned short clist[TOPK];
    __shared__ unsigned short cstart[NC + 1];
    __shared__ unsigned ccnt[NC];
    __shared__ int ps16[17];
    __shared__ int smax;

    int n = blockIdx.x, t = threadIdx.x;
    int lane = t & 63, wid = t >> 6;
    for (int i = t; i < NC * 16; i += 1024) cbits[i] = 0ULL;
    if (t == 0) smax = 0;
    if (t < TOPK) {
        int o = (n << 10) + t;
        float4 ob = obx4[o];
        ob0[t] = ob.x; ob1[t] = ob.y; ob2[t] = ob.z; ob3[t] = ob.w;
        area[t] = areag[o];
        unsigned lk = lblkeep[o];
        lbl[t] = (unsigned short)(lk & 0xFFFFu);
        keepf[t] = (unsigned char)(lk >> 16);
        sup[t] = 0ULL;
    }
    __syncthreads();

    // build class bitsets (bit position == sorted order)
    if (t < TOPK && lbl[t])
        atomicOr(&cbits[(lbl[t] - 1) * 16 + (t >> 6)], 1ull << (t & 63));
    __syncthreads();
    if (t < NC) {
        unsigned s = 0;
#pragma unroll
        for (int w = 0; w < 16; ++w) s += (unsigned)__popcll(cbits[t * 16 + w]);
        ccnt[t] = s;
    }
    __syncthreads();
    if (t < NC) atomicMax(&smax, (int)ccnt[t]);
    __syncthreads();
    if (t == 0) {
        unsigned s = 0;
        for (int c = 0; c < NC; ++c) { cstart[c] = (unsigned short)s; s += ccnt[c]; }
        cstart[NC] = (unsigned short)s;
    }
    __syncthreads();
    // rank = popcount of earlier bits in my class's bitset
    if (t < TOPK && lbl[t]) {
        int my = lbl[t] - 1;
        int w = 0;
        int hi = t >> 6;
        for (int q = 0; q < hi; ++q) w += (int)__popcll(cbits[my * 16 + q]);
        w += (int)__popcll(cbits[my * 16 + hi] & ((1ull << (t & 63)) - 1ull));
        wrank[t] = (unsigned short)w;
        clist[cstart[my] + w] = (unsigned short)t;
    }
    __syncthreads();

    if (smax <= 64) {
        if (t < TOPK && lbl[t]) {
            int base = cstart[lbl[t] - 1];
            int w = wrank[t];
            float A0 = ob0[t], A1 = ob1[t], A2 = ob2[t], A3 = ob3[t], Aa = area[t];
            unsigned long long m = 0ULL;
            for (int j = 0; j < w; ++j) {
                int ib = clist[base + j];
                float iw = fminf(A2, ob2[ib]) - fmaxf(A0, ob0[ib]);
                float ih = fminf(A3, ob3[ib]) - fmaxf(A1, ob1[ib]);
                float inter = fmaxf(iw, 0.0f) * fmaxf(ih, 0.0f);
                float denom = Aa + area[ib] - inter + 1e-6f;
                if (inter / denom > 0.6f) m |= (1ull << j);
            }
            sup[t] = m;
        }
        __syncthreads();
        if (t < NC) {
            unsigned long long kb = 0ULL;
            int base = cstart[t], mc = (int)ccnt[t];
            for (int w = 0; w < mc; ++w) {
                int i = clist[base + w];
                bool kp = keepf[i] && ((sup[i] & kb) == 0ULL);
                keepf[i] = kp ? 1 : 0;
                if (kp) kb |= (1ull << w);
            }
        }
    } else {
        __syncthreads();
        if (t < NC) {   // rare exact fallback
            int s0 = cstart[t], s1 = s0 + (int)ccnt[t];
            for (int a = s0; a < s1; ++a) {
                int ia = clist[a];
                if (!keepf[ia]) continue;
                float A0 = ob0[ia], A1 = ob1[ia], A2 = ob2[ia], A3 = ob3[ia];
                float Aa = area[ia];
                for (int b = a + 1; b < s1; ++b) {
                    int ib = clist[b];
                    if (!keepf[ib]) continue;
                    float iw = fminf(A2, ob2[ib]) - fmaxf(A0, ob0[ib]);
                    float ih = fminf(A3, ob3[ib]) - fmaxf(A1, ob1[ib]);
                    float inter = fmaxf(iw, 0.0f) * fmaxf(ih, 0.0f);
                    float denom = Aa + area[ib] - inter + 1e-6f;
                    if (inter / denom > 0.6f) keepf[ib] = 0;
                }
            }
        }
    }
    __syncthreads();

    // wave-shfl inclusive prefix over keep flags -> output slots
    int v = (t < TOPK) ? (int)keepf[t] : 0;
    int incl = v;
#pragma unroll
    for (int off = 1; off < 64; off <<= 1) {
        int o = __shfl_up(incl, off);
        if (lane >= off) incl += o;
    }
    if (lane == 63) ps16[wid] = incl;
    __syncthreads();
    if (t == 0) {
        int c = 0;
        for (int w = 0; w < 16; ++w) { int x = ps16[w]; ps16[w] = c; c += x; }
        ps16[16] = c;
    }
    __syncthreads();
    int myincl = incl + ps16[wid];
    int total = ps16[16];

    if (t < TOPK && keepf[t]) {
        int q = myincl - 1;
        if (q < NPOST) {
            int o = (n << 10) + t;
            float4 b = box4[o];
            float fused = unflipKey((unsigned)(sorted[o] >> 32));
            outBoxes[(n * NPOST + q) * 4 + 0] = b.x;
            outBoxes[(n * NPOST + q) * 4 + 1] = b.y;
            outBoxes[(n * NPOST + q) * 4 + 2] = b.z;
            outBoxes[(n * NPOST + q) * 4 + 3] = b.w;
            outScores[n * NPOST + q] = sqrtf(fmaxf(fused, 0.0f));
            outLabels[n * NPOST + q] = (float)lbl[t];
        }
    }
    if (t < NPOST && t >= total) {
        outBoxes[(n * NPOST + t) * 4 + 0] = 0.0f;
        outBoxes[(n * NPOST + t) * 4 + 1] = 0.0f;
        outBoxes[(n * NPOST + t) * 4 + 2] = 0.0f;
        outBoxes[(n * NPOST + t) * 4 + 3] = 0.0f;
        outScores[n * NPOST + t] = 0.0f;
        outLabels[n * NPOST + t] = 0.0f;
    }
}

extern "C" void kernel_launch(void* const* d_in, const int* in_sizes, int n_in,
                              void* d_out, int out_size, void* d_ws, size_t ws_size,
                              hipStream_t stream) {
    const float* breg = (const float*)d_in[0];   // [8,4,100,152]
    const float* cent = (const float*)d_in[1];   // [8,1,100,152]
    // d_in[2] box_cls: unused by reference
    const float* dp   = (const float*)d_in[3];   // [8,15200,256]
    const float* anc  = (const float*)d_in[4];   // [15200,4]
    const float* pm   = (const float*)d_in[5];   // [80,256]

    char* ws = (char*)d_ws;
    size_t off_scores   = 0;                                   // 38,912,000
    size_t off_gh       = off_scores + (size_t)TOTAL * 4;      // 131,072
    size_t off_meta     = off_gh + (size_t)NIMG * 4096 * 4;    // 64 (pad 128)
    size_t off_done     = off_meta + 128;                      // 32 (pad 128)
    size_t off_cand     = off_done + 128;                      // 262,144
    size_t off_nnz      = off_cand + (size_t)NIMG * CAP * 8;   // 320 (pad 512)
    size_t off_tok      = off_nnz + 512;                       // 81,920
    size_t off_wt       = off_tok + (size_t)NC * NL * 4;       // 81,920
    size_t off_wavecnt  = off_wt + (size_t)NC * NL * 4;        // 152,000 (+64)
    size_t off_wavemask = off_wavecnt + (size_t)NWAVE * 4 + 64;// 1,216,000
    size_t needed       = off_wavemask + (size_t)NWAVE * 32;
    if (ws_size < needed) return;

    // post-compaction arrays alias the scores region (scores dead after
    // kgather; rewritten from scratch by kscoreh each replay)
    size_t off_sorted = off_scores;                            // 65,536
    size_t off_box4   = off_sorted + (size_t)NIMG * 1024 * 8;  // 131,072
    size_t off_obx4   = off_box4 + (size_t)NIMG * 1024 * 16;   // 131,072
    size_t off_area   = off_obx4 + (size_t)NIMG * 1024 * 16;   // 32,768
    size_t off_lblk   = off_area + (size_t)NIMG * 1024 * 4;    // 32,768

    float*    scores  = (float*)(ws + off_scores);
    unsigned* gh      = (unsigned*)(ws + off_gh);
    unsigned* meta    = (unsigned*)(ws + off_meta);
    unsigned* done    = (unsigned*)(ws + off_done);
    unsigned long long* cand = (unsigned long long*)(ws + off_cand);
    unsigned* nnz     = (unsigned*)(ws + off_nnz);
    unsigned* tok     = (unsigned*)(ws + off_tok);
    float*    wt      = (float*)(ws + off_wt);
    unsigned* wavecnt = (unsigned*)(ws + off_wavecnt);
    unsigned long long* wavemask = (unsigned long long*)(ws + off_wavemask);
    unsigned long long* sorted = (unsigned long long*)(ws + off_sorted);
    float4*   box4    = (float4*)(ws + off_box4);
    float4*   obx4    = (float4*)(ws + off_obx4);
    float*    areag   = (float*)(ws + off_area);
    unsigned* lblkeep = (unsigned*)(ws + off_lblk);

    kinit<<<128, 256, 0, stream>>>(pm, nnz, tok, wt, gh, done);
    kscoreh<<<SBLK32, 512, 0, stream>>>(dp, cent, nnz, tok, wt, scores,
                                        gh, done, meta);
    kcountM<<<CBLK, 256, 0, stream>>>((const float4*)scores, meta,
                                      wavecnt, wavemask);
    kgather<<<NIMG, 1024, 0, stream>>>(wavecnt, wavemask, scores, meta,
                                       cand, sorted);
    kdecode<<<(NIMG * TOPK + 255) / 256, 256, 0, stream>>>(sorted, anc, breg,
                                                           box4, obx4, areag, lblkeep);

    float* outBoxes  = (float*)d_out;                       // 8*100*4
    float* outScores = outBoxes + NIMG * NPOST * 4;         // 8*100
    float* outLabels = outScores + NIMG * NPOST;            // 8*100
    knms2<<<NIMG, 1024, 0, stream>>>(sorted, obx4, areag, lblkeep, box4,
                                     outBoxes, outScores, outLabels);
}

// Round 16
// 184.482 us; speedup vs baseline: 1.5855x; 1.5855x over previous
//
#include <hip/hip_runtime.h>
#include <hip/hip_bf16.h>

#define NIMG 8
#define NC   80
#define NL   256
#define HWQ  15200
#define TOPK 1000
#define CAP  4096
#define SSORT 2048
#define NPOST 100
#define PERIMG (HWQ * NC)          // 1,216,000
#define TOTAL (NIMG * PERIMG)      // 9,728,000
#define SROW 32                    // rows per score block
#define SBLK32 (NIMG * HWQ / SROW) // 3800
#define PI4  (PERIMG / 4)          // 304,000 float4 per image
#define WPI  (PI4 / 64)            // 4750 waves per image
#define NWAVE (NIMG * WPI)         // 38,000
#define CBLK (TOTAL / 4 / 256)     // 9,500 blocks for count pass

__device__ __forceinline__ unsigned flipKey(float f) {
    unsigned u = __float_as_uint(f);
    return u ^ (((unsigned)((int)u >> 31)) | 0x80000000u);
}
__device__ __forceinline__ float unflipKey(unsigned k) {
    unsigned u = k ^ ((k & 0x80000000u) ? 0x80000000u : 0xFFFFFFFFu);
    return __uint_as_float(u);
}
__device__ __forceinline__ float sigmoidf(float x) {
    return 1.0f / (1.0f + expf(-x));
}

// ---- init: zero coarse histograms + extract (token, weight) lists ----
__global__ void __launch_bounds__(256)
kinit(const float* __restrict__ pm, unsigned* nnz, unsigned* tok, float* wt,
      unsigned* __restrict__ gh) {
    int g = blockIdx.x * 256 + threadIdx.x;
    if (g < NIMG * 4096) gh[g] = 0;            // 32768 threads == exact
    if (g < NC) {
        int c = g;
        int cnt = 0;
        for (int l = 0; l < NL; ++l) {
            float v = pm[c * NL + l];
            if (v != 0.0f) { tok[cnt * NC + c] = l; wt[cnt * NC + c] = v; cnt++; }
        }
        nnz[c] = cnt;
    }
}

// ---- fused scores + centerness + coarse 12-bit histogram (v3, round-10) ----
__global__ void __launch_bounds__(512)
kscoreh(const float* __restrict__ dp, const float* __restrict__ cent,
        const unsigned* __restrict__ nnz, const unsigned* __restrict__ tok,
        const float* __restrict__ wt, float* __restrict__ scores,
        unsigned* __restrict__ gh) {
    __shared__ unsigned h[4096];        // 16 KB
    __shared__ float sctr[SROW];
    int t = threadIdx.x;
    for (int i = t; i < 4096; i += 512) h[i] = 0;
    long long base = (long long)blockIdx.x * SROW;        // first global row
    if (t < SROW) sctr[t] = sigmoidf(cent[base + t]);     // once per row
    long long obase = base * NC;
    const float* dpb = dp + base * NL;

    int  rr[5], cc[5], mm[5];
    int  tk[5][3];
    float wv[5][3], xv[5][3];
#pragma unroll
    for (int j = 0; j < 5; ++j) {
        int o = t + j * 512;            // 0..2559 (32 rows x 80 classes)
        rr[j] = o / NC; cc[j] = o - rr[j] * NC;
        mm[j] = (int)nnz[cc[j]];
        int c = cc[j];
        tk[j][0] = (int)tok[c] & 255;           // clamp: safe vs stale ws
        tk[j][1] = (int)tok[NC + c] & 255;
        tk[j][2] = (int)tok[2 * NC + c] & 255;
        wv[j][0] = wt[c]; wv[j][1] = wt[NC + c]; wv[j][2] = wt[2 * NC + c];
    }
#pragma unroll
    for (int j = 0; j < 5; ++j) {       // all gathers issued before any exp
        const float* row = dpb + rr[j] * NL;
        if (tk[j][1] == tk[j][0] + 1 && tk[j][2] == tk[j][0] + 2) {
            float3 v3 = *(const float3*)(row + tk[j][0]);   // 1 VMEM, 12B
            xv[j][0] = v3.x; xv[j][1] = v3.y; xv[j][2] = v3.z;
        } else {
            xv[j][0] = row[tk[j][0]];
            xv[j][1] = row[tk[j][1]];
            xv[j][2] = row[tk[j][2]];
        }
    }
    __syncthreads();                    // sctr ready; hist zeroed
#pragma unroll
    for (int j = 0; j < 5; ++j) {
        float acc = 0.0f;
        if (mm[j] == 3) {               // identical arithmetic to prior rounds
            float s0 = sigmoidf(xv[j][0]);
            float s1 = sigmoidf(xv[j][1]);
            float s2 = sigmoidf(xv[j][2]);
            acc += s0 * wv[j][0]; acc += s1 * wv[j][1]; acc += s2 * wv[j][2];
        } else {
            const float* row = dpb + rr[j] * NL;
            for (int q = 0; q < mm[j]; ++q)
                acc += sigmoidf(row[tok[q * NC + cc[j]]]) * wt[q * NC + cc[j]];
        }
        float sc = (acc > 0.05f) ? acc * sctr[rr[j]] : -1.0f;
        scores[obase + t + j * 512] = sc;
        atomicAdd(&h[flipKey(sc) >> 20], 1u);
    }
    __syncthreads();
    int n = (int)(base / HWQ);          // 475 blocks per image exactly
    for (int i = t; i < 4096; i += 512)
        if (h[i]) atomicAdd(&gh[n * 4096 + i], h[i]);
}

// ---- find coarse bucket containing rank TOPK ----
__global__ void kfind1(const unsigned* __restrict__ gh, unsigned* meta) {
    __shared__ unsigned h[4096];
    __shared__ unsigned psum[256];
    int n = blockIdx.x;
    for (int i = threadIdx.x; i < 4096; i += 256) h[i] = gh[n * 4096 + i];
    __syncthreads();
    unsigned s = 0;
    for (int i = 0; i < 16; ++i) s += h[threadIdx.x * 16 + i];
    psum[threadIdx.x] = s;
    __syncthreads();
    if (threadIdx.x == 0) {
        unsigned cum = 0, above = 0; int B = 0; bool done = false;
        for (int seg = 255; seg >= 0 && !done; --seg) {
            if (cum + psum[seg] >= TOPK) {
                for (int b = seg * 16 + 15; b >= seg * 16; --b) {
                    if (cum + h[b] >= TOPK) { B = b; above = cum; done = true; break; }
                    cum += h[b];
                }
            } else cum += psum[seg];
        }
        meta[n] = (unsigned)B;
        meta[8 + n] = above;
    }
}

// ---- count pass with per-wave 256-bit selection masks (atomic-free) ----
__global__ void __launch_bounds__(256)
kcountM(const float4* __restrict__ scores4, const unsigned* __restrict__ meta,
        unsigned* __restrict__ wavecnt, unsigned long long* __restrict__ wavemask) {
    int i4 = blockIdx.x * 256 + threadIdx.x;
    int n = i4 / PI4;                 // wave-uniform (64 | PI4)
    unsigned B = meta[n];
    float4 v = scores4[i4];
    bool s0 = (flipKey(v.x) >> 20) >= B;
    bool s1 = (flipKey(v.y) >> 20) >= B;
    bool s2 = (flipKey(v.z) >> 20) >= B;
    bool s3 = (flipKey(v.w) >> 20) >= B;
    unsigned long long m0 = __ballot(s0);
    unsigned long long m1 = __ballot(s1);
    unsigned long long m2 = __ballot(s2);
    unsigned long long m3 = __ballot(s3);
    if ((threadIdx.x & 63) == 0) {
        int w = i4 >> 6;
        wavemask[(size_t)w * 4 + 0] = m0;
        wavemask[(size_t)w * 4 + 1] = m1;
        wavemask[(size_t)w * 4 + 2] = m2;
        wavemask[(size_t)w * 4 + 3] = m3;
        wavecnt[w] = (unsigned)(__popcll(m0) + __popcll(m1)
                              + __popcll(m2) + __popcll(m3));
    }
}

// ---- merged gather: wave-shfl prefix (2 barriers), gather into LDS,
//      sort, emit exact top-1000; global-cand fallback if total > SSORT ----
__global__ void __launch_bounds__(1024)
kgather(const unsigned* __restrict__ wavecnt,
        const unsigned long long* __restrict__ wavemask,
        const float* __restrict__ scores, const unsigned* __restrict__ meta,
        unsigned long long* __restrict__ cand,
        unsigned long long* __restrict__ sorted) {
    __shared__ unsigned ps16[17];
    __shared__ unsigned long long sbuf[SSORT];   // 16 KB
    __shared__ unsigned h[4096];                 // 16 KB (fallback only)
    __shared__ unsigned psum[256];
    __shared__ unsigned selcnt, Fbin;
    int n = blockIdx.x, t = threadIdx.x;
    int lane = t & 63, wid = t >> 6;
    const unsigned* wc = wavecnt + n * WPI;
    const unsigned long long* wm = wavemask + (size_t)n * WPI * 4;
    const float* sb = scores + (size_t)n * PERIMG;
    sbuf[t] = 0ULL; sbuf[t + 1024] = 0ULL;

    // per-thread sums over 5 wave-slots
    int s0 = t * 5;                    // 5*1024 = 5120 >= 4750
    unsigned loc[5], vv[5]; unsigned sum = 0;
#pragma unroll
    for (int j = 0; j < 5; ++j) {
        int i = s0 + j;
        unsigned x = (i < WPI) ? wc[i] : 0u;
        vv[j] = x; loc[j] = sum; sum += x;
    }
    // wave-level inclusive scan of sum (no barriers)
    unsigned wincl = sum;
#pragma unroll
    for (int off = 1; off < 64; off <<= 1) {
        unsigned o = (unsigned)__shfl_up((int)wincl, off);
        if (lane >= off) wincl += o;
    }
    if (lane == 63) ps16[wid] = wincl;
    __syncthreads();
    if (t == 0) {
        unsigned c = 0;
        for (int w = 0; w < 16; ++w) { unsigned x = ps16[w]; ps16[w] = c; c += x; }
        ps16[16] = c;
    }
    __syncthreads();
    unsigned excl = ps16[wid] + (wincl - sum);
    unsigned total = ps16[16];
    int nsel;

    if (total <= SSORT) {
        // common path: gather straight into the LDS sort buffer
#pragma unroll
        for (int j = 0; j < 5; ++j) {
            int wl = s0 + j;
            if (wl < WPI && vv[j]) {
                unsigned off = excl + loc[j];
                const unsigned long long* mk = wm + (size_t)wl * 4;
#pragma unroll
                for (int e = 0; e < 4; ++e) {
                    unsigned long long m = mk[e];
                    while (m) {
                        int b = __ffsll(m) - 1; m &= m - 1;
                        int li = wl * 256 + b * 4 + e;
                        unsigned key = flipKey(sb[li]);
                        sbuf[off++] = ((unsigned long long)key << 32)
                                      | (unsigned)(~li);
                    }
                }
            }
        }
        nsel = (int)total;
        __syncthreads();
    } else {
        // fallback: gather to global cand, then fine-threshold select
        unsigned long long* cb = cand + (size_t)n * CAP;
#pragma unroll
        for (int j = 0; j < 5; ++j) {
            int wl = s0 + j;
            if (wl < WPI && vv[j]) {
                unsigned off = excl + loc[j];
                const unsigned long long* mk = wm + (size_t)wl * 4;
#pragma unroll
                for (int e = 0; e < 4; ++e) {
                    unsigned long long m = mk[e];
                    while (m) {
                        int b = __ffsll(m) - 1; m &= m - 1;
                        int li = wl * 256 + b * 4 + e;
                        unsigned key = flipKey(sb[li]);
                        if (off < CAP)
                            cb[off] = ((unsigned long long)key << 32)
                                      | (unsigned)(~li);
                        off++;
                    }
                }
            }
        }
        for (int i = t; i < 4096; i += 1024) h[i] = 0;
        if (t == 0) selcnt = 0;
        __syncthreads();
        int M = min((int)total, CAP);
        unsigned B = meta[n], above = meta[8 + n];
        for (int i = t; i < M; i += 1024) {
            unsigned key = (unsigned)(cb[i] >> 32);
            if ((key >> 20) == B) atomicAdd(&h[(key >> 8) & 0xFFFu], 1u);
        }
        __syncthreads();
        if (t < 256) {
            unsigned s = 0;
            for (int i = 0; i < 16; ++i) s += h[t * 16 + i];
            psum[t] = s;
        }
        __syncthreads();
        if (t == 0) {
            unsigned cum = above; int F = 0; bool done = false;
            for (int seg = 255; seg >= 0 && !done; --seg) {
                if (cum + psum[seg] >= TOPK) {
                    for (int b = seg * 16 + 15; b >= seg * 16; --b) {
                        if (cum + h[b] >= TOPK) { F = b; done = true; break; }
                        cum += h[b];
                    }
                } else cum += psum[seg];
            }
            Fbin = (unsigned)F;
        }
        __syncthreads();
        unsigned T24 = (meta[n] << 12) | Fbin;
        for (int i = t; i < M; i += 1024) {
            unsigned long long e = cb[i];
            unsigned key = (unsigned)(e >> 32);
            if ((key >> 8) >= T24) {
                unsigned p = atomicAdd(&selcnt, 1u);
                if (p < SSORT) sbuf[p] = e;
            }
        }
        __syncthreads();
        nsel = (int)selcnt;
    }

    // bitonic sort descending on unique (key<<32)|~idx
    int SN = (nsel <= 1024) ? 1024 : SSORT;
    for (int k = 2; k <= SN; k <<= 1) {
        for (int j = k >> 1; j > 0; j >>= 1) {
            for (int i = t; i < SN; i += 1024) {
                int l = i ^ j;
                if (l > i) {
                    unsigned long long a = sbuf[i], b = sbuf[l];
                    bool sw = ((i & k) == 0) ? (a < b) : (a > b);
                    if (sw) { sbuf[i] = b; sbuf[l] = a; }
                }
            }
            __syncthreads();
        }
    }
    if (t < TOPK) sorted[(n << 10) + t] = sbuf[t];
}

// ---- decode all 8x1000 candidates chip-wide ----
__global__ void __launch_bounds__(256)
kdecode(const unsigned long long* __restrict__ sorted,
        const float* __restrict__ anchors, const float* __restrict__ breg,
        float4* __restrict__ box4, float4* __restrict__ obx4,
        float* __restrict__ areag, unsigned* __restrict__ lblkeep) {
    int gid = blockIdx.x * 256 + threadIdx.x;
    if (gid >= NIMG * TOPK) return;
    int n = gid / TOPK, r = gid - n * TOPK;
    int o = (n << 10) + r;
    unsigned long long e = sorted[o];
    unsigned key = (unsigned)(e >> 32);
    bool real = key > 0x80000000u;       // masked value > 0
    unsigned li = ~(unsigned)(e & 0xFFFFFFFFu);
    unsigned k = li / NC, c = li - k * NC;
    int label = (int)c + 1;
    float x1 = 0, y1 = 0, x2 = 0, y2 = 0;
    bool val = false;
    if (real) {
        float a0 = anchors[k * 4 + 0], a1 = anchors[k * 4 + 1];
        float a2 = anchors[k * 4 + 2], a3 = anchors[k * 4 + 3];
        float r0 = breg[(n * 4 + 0) * HWQ + k];
        float r1 = breg[(n * 4 + 1) * HWQ + k];
        float r2 = breg[(n * 4 + 2) * HWQ + k];
        float r3 = breg[(n * 4 + 3) * HWQ + k];
        float aw = a2 - a0, ah = a3 - a1;
        float acx = a0 + 0.5f * aw, acy = a1 + 0.5f * ah;
        float dx = r0 / 10.0f, dy = r1 / 10.0f;
        float dw = fminf(r2 / 5.0f, 4.135166556742356f);
        float dh = fminf(r3 / 5.0f, 4.135166556742356f);
        float pcx = dx * aw + acx, pcy = dy * ah + acy;
        float pw = expf(dw) * aw, ph = expf(dh) * ah;
        x1 = fminf(fmaxf(pcx - 0.5f * pw, 0.0f), 1216.0f);
        y1 = fminf(fmaxf(pcy - 0.5f * ph, 0.0f), 800.0f);
        x2 = fminf(fmaxf(pcx + 0.5f * pw, 0.0f), 1216.0f);
        y2 = fminf(fmaxf(pcy + 0.5f * ph, 0.0f), 800.0f);
        val = (x2 - x1 > 0.0f) && (y2 - y1 > 0.0f);
    }
    box4[o] = make_float4(x1, y1, x2, y2);
    float off = (float)label * 10000.0f;   // replicate offset-then-round
    float o0 = x1 + off, o1 = y1 + off, o2 = x2 + off, o3 = y2 + off;
    obx4[o] = make_float4(o0, o1, o2, o3);
    areag[o] = (o2 - o0) * (o3 - o1);
    lblkeep[o] = (unsigned)(real ? label : 0) | ((val ? 1u : 0u) << 16);
}

// ---- per-image: class-decomposed bitmask NMS + output (bitset ranks,
//      wave-shfl keep-prefix: 2 barriers instead of 20) ----
__global__ void __launch_bounds__(1024)
knms2(const unsigned long long* __restrict__ sorted,
      const float4* __restrict__ obx4, const float* __restrict__ areag,
      const unsigned* __restrict__ lblkeep, const float4* __restrict__ box4,
      float* __restrict__ outBoxes, float* __restrict__ outScores,
      float* __restrict__ outLabels) {
    __shared__ float ob0[TOPK], ob1[TOPK], ob2[TOPK], ob3[TOPK], area[TOPK];
    __shared__ unsigned long long sup[TOPK];
    __shared__ unsigned long long cbits[NC * 16];   // 10,240 B class bitsets
    __shared__ unsigned short lbl[TOPK];
    __shared__ unsigned char  keepf[TOPK];
    __shared__ unsigned short wrank[TOPK];
    __shared__ unsigned short clist[TOPK];
    __shared__ unsigned short cstart[NC + 1];
    __shared__ unsigned ccnt[NC];
    __shared__ int ps16[17];
    __shared__ int smax;

    int n = blockIdx.x, t = threadIdx.x;
    int lane = t & 63, wid = t >> 6;
    for (int i = t; i < NC * 16; i += 1024) cbits[i] = 0ULL;
    if (t == 0) smax = 0;
    if (t < TOPK) {
        int o = (n << 10) + t;
        float4 ob = obx4[o];
        ob0[t] = ob.x; ob1[t] = ob.y; ob2[t] = ob.z; ob3[t] = ob.w;
        area[t] = areag[o];
        unsigned lk = lblkeep[o];
        lbl[t] = (unsigned short)(lk & 0xFFFFu);
        keepf[t] = (unsigned char)(lk >> 16);
        sup[t] = 0ULL;
    }
    __syncthreads();

    // build class bitsets (bit position == sorted order)
    if (t < TOPK && lbl[t])
        atomicOr(&cbits[(lbl[t] - 1) * 16 + (t >> 6)], 1ull << (t & 63));
    __syncthreads();
    if (t < NC) {
        unsigned s = 0;
#pragma unroll
        for (int w = 0; w < 16; ++w) s += (unsigned)__popcll(cbits[t * 16 + w]);
        ccnt[t] = s;
    }
    __syncthreads();
    if (t < NC) atomicMax(&smax, (int)ccnt[t]);
    __syncthreads();
    if (t == 0) {
        unsigned s = 0;
        for (int c = 0; c < NC; ++c) { cstart[c] = (unsigned short)s; s += ccnt[c]; }
        cstart[NC] = (unsigned short)s;
    }
    __syncthreads();
    // rank = popcount of earlier bits in my class's bitset
    if (t < TOPK && lbl[t]) {
        int my = lbl[t] - 1;
        int w = 0;
        int hi = t >> 6;
        for (int q = 0; q < hi; ++q) w += (int)__popcll(cbits[my * 16 + q]);
        w += (int)__popcll(cbits[my * 16 + hi] & ((1ull << (t & 63)) - 1ull));
        wrank[t] = (unsigned short)w;
        clist[cstart[my] + w] = (unsigned short)t;
    }
    __syncthreads();

    if (smax <= 64) {
        if (t < TOPK && lbl[t]) {
            int base = cstart[lbl[t] - 1];
            int w = wrank[t];
            float A0 = ob0[t], A1 = ob1[t], A2 = ob2[t], A3 = ob3[t], Aa = area[t];
            unsigned long long m = 0ULL;
            for (int j = 0; j < w; ++j) {
                int ib = clist[base + j];
                float iw = fminf(A2, ob2[ib]) - fmaxf(A0, ob0[ib]);
                float ih = fminf(A3, ob3[ib]) - fmaxf(A1, ob1[ib]);
                float inter = fmaxf(iw, 0.0f) * fmaxf(ih, 0.0f);
                float denom = Aa + area[ib] - inter + 1e-6f;
                if (inter / denom > 0.6f) m |= (1ull << j);
            }
            sup[t] = m;
        }
        __syncthreads();
        if (t < NC) {
            unsigned long long kb = 0ULL;
            int base = cstart[t], mc = (int)ccnt[t];
            for (int w = 0; w < mc; ++w) {
                int i = clist[base + w];
                bool kp = keepf[i] && ((sup[i] & kb) == 0ULL);
                keepf[i] = kp ? 1 : 0;
                if (kp) kb |= (1ull << w);
            }
        }
    } else {
        __syncthreads();
        if (t < NC) {   // rare exact fallback
            int s0 = cstart[t], s1 = s0 + (int)ccnt[t];
            for (int a = s0; a < s1; ++a) {
                int ia = clist[a];
                if (!keepf[ia]) continue;
                float A0 = ob0[ia], A1 = ob1[ia], A2 = ob2[ia], A3 = ob3[ia];
                float Aa = area[ia];
                for (int b = a + 1; b < s1; ++b) {
                    int ib = clist[b];
                    if (!keepf[ib]) continue;
                    float iw = fminf(A2, ob2[ib]) - fmaxf(A0, ob0[ib]);
                    float ih = fminf(A3, ob3[ib]) - fmaxf(A1, ob1[ib]);
                    float inter = fmaxf(iw, 0.0f) * fmaxf(ih, 0.0f);
                    float denom = Aa + area[ib] - inter + 1e-6f;
                    if (inter / denom > 0.6f) keepf[ib] = 0;
                }
            }
        }
    }
    __syncthreads();

    // wave-shfl inclusive prefix over keep flags -> output slots
    int v = (t < TOPK) ? (int)keepf[t] : 0;
    int incl = v;
#pragma unroll
    for (int off = 1; off < 64; off <<= 1) {
        int o = __shfl_up(incl, off);
        if (lane >= off) incl += o;
    }
    if (lane == 63) ps16[wid] = incl;
    __syncthreads();
    if (t == 0) {
        int c = 0;
        for (int w = 0; w < 16; ++w) { int x = ps16[w]; ps16[w] = c; c += x; }
        ps16[16] = c;
    }
    __syncthreads();
    int myincl = incl + ps16[wid];
    int total = ps16[16];

    if (t < TOPK && keepf[t]) {
        int q = myincl - 1;
        if (q < NPOST) {
            int o = (n << 10) + t;
            float4 b = box4[o];
            float fused = unflipKey((unsigned)(sorted[o] >> 32));
            outBoxes[(n * NPOST + q) * 4 + 0] = b.x;
            outBoxes[(n * NPOST + q) * 4 + 1] = b.y;
            outBoxes[(n * NPOST + q) * 4 + 2] = b.z;
            outBoxes[(n * NPOST + q) * 4 + 3] = b.w;
            outScores[n * NPOST + q] = sqrtf(fmaxf(fused, 0.0f));
            outLabels[n * NPOST + q] = (float)lbl[t];
        }
    }
    if (t < NPOST && t >= total) {
        outBoxes[(n * NPOST + t) * 4 + 0] = 0.0f;
        outBoxes[(n * NPOST + t) * 4 + 1] = 0.0f;
        outBoxes[(n * NPOST + t) * 4 + 2] = 0.0f;
        outBoxes[(n * NPOST + t) * 4 + 3] = 0.0f;
        outScores[n * NPOST + t] = 0.0f;
        outLabels[n * NPOST + t] = 0.0f;
    }
}

extern "C" void kernel_launch(void* const* d_in, const int* in_sizes, int n_in,
                              void* d_out, int out_size, void* d_ws, size_t ws_size,
                              hipStream_t stream) {
    const float* breg = (const float*)d_in[0];   // [8,4,100,152]
    const float* cent = (const float*)d_in[1];   // [8,1,100,152]
    // d_in[2] box_cls: unused by reference
    const float* dp   = (const float*)d_in[3];   // [8,15200,256]
    const float* anc  = (const float*)d_in[4];   // [15200,4]
    const float* pm   = (const float*)d_in[5];   // [80,256]

    char* ws = (char*)d_ws;
    size_t off_scores   = 0;                                   // 38,912,000
    size_t off_gh       = off_scores + (size_t)TOTAL * 4;      // 131,072
    size_t off_meta     = off_gh + (size_t)NIMG * 4096 * 4;    // 64 (pad 128)
    size_t off_cand     = off_meta + 128;                      // 262,144
    size_t off_nnz      = off_cand + (size_t)NIMG * CAP * 8;   // 320 (pad 512)
    size_t off_tok      = off_nnz + 512;                       // 81,920
    size_t off_wt       = off_tok + (size_t)NC * NL * 4;       // 81,920
    size_t off_wavecnt  = off_wt + (size_t)NC * NL * 4;        // 152,000 (+64)
    size_t off_wavemask = off_wavecnt + (size_t)NWAVE * 4 + 64;// 1,216,000
    size_t needed       = off_wavemask + (size_t)NWAVE * 32;
    if (ws_size < needed) return;

    // post-compaction arrays alias the scores region (scores dead after
    // kgather; rewritten from scratch by kscoreh each replay)
    size_t off_sorted = off_scores;                            // 65,536
    size_t off_box4   = off_sorted + (size_t)NIMG * 1024 * 8;  // 131,072
    size_t off_obx4   = off_box4 + (size_t)NIMG * 1024 * 16;   // 131,072
    size_t off_area   = off_obx4 + (size_t)NIMG * 1024 * 16;   // 32,768
    size_t off_lblk   = off_area + (size_t)NIMG * 1024 * 4;    // 32,768

    float*    scores  = (float*)(ws + off_scores);
    unsigned* gh      = (unsigned*)(ws + off_gh);
    unsigned* meta    = (unsigned*)(ws + off_meta);
    unsigned long long* cand = (unsigned long long*)(ws + off_cand);
    unsigned* nnz     = (unsigned*)(ws + off_nnz);
    unsigned* tok     = (unsigned*)(ws + off_tok);
    float*    wt      = (float*)(ws + off_wt);
    unsigned* wavecnt = (unsigned*)(ws + off_wavecnt);
    unsigned long long* wavemask = (unsigned long long*)(ws + off_wavemask);
    unsigned long long* sorted = (unsigned long long*)(ws + off_sorted);
    float4*   box4    = (float4*)(ws + off_box4);
    float4*   obx4    = (float4*)(ws + off_obx4);
    float*    areag   = (float*)(ws + off_area);
    unsigned* lblkeep = (unsigned*)(ws + off_lblk);

    kinit<<<128, 256, 0, stream>>>(pm, nnz, tok, wt, gh);
    kscoreh<<<SBLK32, 512, 0, stream>>>(dp, cent, nnz, tok, wt, scores, gh);
    kfind1<<<NIMG, 256, 0, stream>>>(gh, meta);
    kcountM<<<CBLK, 256, 0, stream>>>((const float4*)scores, meta,
                                      wavecnt, wavemask);
    kgather<<<NIMG, 1024, 0, stream>>>(wavecnt, wavemask, scores, meta,
                                       cand, sorted);
    kdecode<<<(NIMG * TOPK + 255) / 256, 256, 0, stream>>>(sorted, anc, breg,
                                                           box4, obx4, areag, lblkeep);

    float* outBoxes  = (float*)d_out;                       // 8*100*4
    float* outScores = outBoxes + NIMG * NPOST * 4;         // 8*100
    float* outLabels = outScores + NIMG * NPOST;            // 8*100
    knms2<<<NIMG, 1024, 0, stream>>>(sorted, obx4, areag, lblkeep, box4,
                                     outBoxes, outScores, outLabels);
}